// Round 16
// baseline (177.867 us; speedup 1.0000x reference)
//
#include <hip/hip_runtime.h>
#include <hip/hip_bf16.h>

#define N_NODES 16384
#define N_EDGES 262144
#define GD 300        // real feature dim
#define DP 320        // padded feature dim (pads are exact zeros)
#define N_GRAPHS 64
#define NTILE 5       // 5 column tiles of 64

typedef short bf16x8 __attribute__((ext_vector_type(8)));
typedef float f32x4 __attribute__((ext_vector_type(4)));

__device__ static inline unsigned short f2bf(float v) {
  __hip_bfloat16 b = __float2bfloat16(v);
  return __builtin_bit_cast(unsigned short, b);
}
__device__ static inline float bf2f(unsigned short u) {
  return __bfloat162float(__builtin_bit_cast(__hip_bfloat16, u));
}

#define GLOAD_LDS16(g, l)                                                    \
  __builtin_amdgcn_global_load_lds(                                          \
      (const __attribute__((address_space(1))) void*)(g),                    \
      (__attribute__((address_space(3))) void*)(l), 16, 0, 0)

// ============== fused two-stage bf16 MFMA GEMM (R12 structure) ==============
// Stage 1: C1 = act1(A @ W1 + b1); A staged once in LDS (gload_lds or CONVF
//          fp32-convert). act1 = relu iff RELU1 (lift fusion needs identity).
// FUSE2:   h=C1 kept in LDS (staged-A layout) -> C = relu(h @ W2 + b2)
// RO:      no C; fused readout d = relu(C1+b1).Wro -> softmax -> graph bins
// BM=64 rows/block, BN=320 (full width), 512 thr = 8 waves (2 row x 4 col),
// per-wave 2x5 frags of 16x16x32. B double-buffered 2x40KB, counted
// s_waitcnt vmcnt(5) across raw barriers (R12-verified pipeline).
// LDS rows 128B, 16B-slot s holds global slot s^(row&7) (conflict-free b128).
constexpr int ATILE = 8192;                  // one 64-row x 64-k A tile
constexpr int AFULL = 5 * ATILE;             // 40960
constexpr int BBUF = 40960;                  // one 320-row x 64-k B tile
constexpr int EPITCH = 328;                  // bounce pitch (>= BN=320!)
constexpr size_t WSZ = (size_t)DP * DP;
static_assert(64 * EPITCH * 2 <= AFULL + 2 * BBUF, "epilogue bounce fits");

template <bool RELU1, bool TILED, bool FUSE2, bool RO, bool CONVF>
__global__ __launch_bounds__(512, 2) void gemm_f(
    const unsigned short* __restrict__ A, const float* __restrict__ nf,
    const unsigned short* __restrict__ Wt1,
    const float* __restrict__ bias1, const unsigned short* __restrict__ Wt2,
    const float* __restrict__ bias2, unsigned short* __restrict__ C,
    const float* __restrict__ Wro, const float* __restrict__ bro,
    const int* __restrict__ gid, float* __restrict__ out) {
  __shared__ __align__(16) char smem[AFULL + 2 * BBUF];  // 122880 B
  __shared__ float wroL[2 * DP];
  __shared__ float rowacc[2 * 64];
  __shared__ float binsL[2 * N_GRAPHS];

  const int bm = blockIdx.x * 64;
  const int t = threadIdx.x;
  const int w = t >> 6, l = t & 63;
  const int wr = w & 1;        // row group: rows wr*32..+31
  const int wc = w >> 1;       // col group 0..3: cols wc*80..+79
  const int cl = l & 15, q = l >> 4;
  const int lr = l >> 3;             // row within 8-row staging group
  const int sg = (l & 7) ^ lr;       // pre-swizzled global 16B slot

  if (RO) {
    for (int i = t; i < DP; i += 512) {
      wroL[2 * i] = (i < GD) ? Wro[2 * i] : 0.f;
      wroL[2 * i + 1] = (i < GD) ? Wro[2 * i + 1] : 0.f;
    }
    if (t < 128) rowacc[t] = 0.f;
    if (t < 2 * N_GRAPHS) binsL[t] = 0.f;
  }

  auto stageB = [&](const unsigned short* W, int tk, int buf) {
    char* lb = smem + AFULL + buf * BBUF;
#pragma unroll
    for (int i = 0; i < 5; ++i) {
      int c = w + 8 * i;  // 1KB chunk = 8 rows
      GLOAD_LDS16(W + (size_t)(c * 8 + lr) * DP + tk * 64 + 8 * sg,
                  lb + c * 1024);
    }
  };

  f32x4 acc[2][5] = {};

  auto compute = [&](const char* lA, const char* lB) {
#pragma unroll
    for (int ks = 0; ks < 2; ++ks) {
      bf16x8 a[2], b[5];
#pragma unroll
      for (int m = 0; m < 2; ++m) {
        int r = wr * 32 + m * 16 + cl;
        int slot = (ks * 4 + q) ^ (r & 7);
        a[m] = *(const bf16x8*)(lA + r * 128 + slot * 16);
      }
#pragma unroll
      for (int n = 0; n < 5; ++n) {
        int r = wc * 80 + n * 16 + cl;
        int slot = (ks * 4 + q) ^ (r & 7);
        b[n] = *(const bf16x8*)(lB + r * 128 + slot * 16);
      }
#pragma unroll
      for (int m = 0; m < 2; ++m)
#pragma unroll
        for (int n = 0; n < 5; ++n)
          acc[m][n] = __builtin_amdgcn_mfma_f32_16x16x32_bf16(a[m], b[n],
                                                              acc[m][n], 0, 0, 0);
    }
  };

  // ---- prologue: B tile 0 first (loads in flight), then stage A ----
  stageB(Wt1, 0, 0);
  if (CONVF) {
    // A from fp32 node_feats: reg-load + convert + ds_write into XOR layout.
    const int r = t >> 3;       // 0..63 (8 threads per row)
    const int ls = t & 7;       // 16B slot within each 128B k-tile
    const float* rp = nf + (size_t)(bm + r) * GD;
#pragma unroll
    for (int p = 0; p < 5; ++p) {
      int c0 = p * 64 + ls * 8;
      bf16x8 o;
      if (c0 + 8 <= GD) {
        float4 a = *(const float4*)(rp + c0);
        float4 b = *(const float4*)(rp + c0 + 4);
        o[0] = f2bf(a.x); o[1] = f2bf(a.y); o[2] = f2bf(a.z); o[3] = f2bf(a.w);
        o[4] = f2bf(b.x); o[5] = f2bf(b.y); o[6] = f2bf(b.z); o[7] = f2bf(b.w);
      } else {
#pragma unroll
        for (int i = 0; i < 8; ++i) {
          int c = c0 + i;
          o[i] = f2bf(c < GD ? rp[c] : 0.f);  // pads MUST be exact zeros
        }
      }
      *(bf16x8*)(smem + p * ATILE + r * 128 + ((ls ^ (r & 7)) << 4)) = o;
    }
    asm volatile("s_waitcnt lgkmcnt(0)" ::: "memory");
  } else {
#pragma unroll
    for (int p = 0; p < 5; ++p)
      GLOAD_LDS16(A + (size_t)(bm + w * 8 + lr) * DP + p * 64 + 8 * sg,
                  smem + p * ATILE + w * 1024);
  }

  // ---- stage-1 K loop (R12-verified: counted vmcnt across raw barriers) ----
  for (int tk = 0; tk < 5; ++tk) {
    __builtin_amdgcn_s_barrier();
    if (tk + 1 < 5) {
      stageB(Wt1, tk + 1, (tk + 1) & 1);
      asm volatile("s_waitcnt vmcnt(5)" ::: "memory");
    } else {
      asm volatile("s_waitcnt vmcnt(0)" ::: "memory");
    }
    __builtin_amdgcn_s_barrier();
    compute(smem + tk * ATILE, smem + AFULL + (tk & 1) * BBUF);
  }

  if (FUSE2) {
    // ---- h = act1(acc + bias1) -> LDS (staged-A layout), then stage 2 ----
    __syncthreads();          // all waves done with A region and Bbuf0
    stageB(Wt2, 0, 0);        // W2 tile 0 in flight during h write
#pragma unroll
    for (int n = 0; n < 5; ++n) {
      int col = wc * 80 + n * 16 + cl;
      float bv = bias1[col];
      int kt = col >> 6, kin = col & 63;
#pragma unroll
      for (int m = 0; m < 2; ++m) {
#pragma unroll
        for (int r = 0; r < 4; ++r) {
          int row = wr * 32 + m * 16 + q * 4 + r;
          float v = acc[m][n][r] + bv;
          if (RELU1) v = fmaxf(v, 0.f);   // lift fusion: RELU1=false
          int byte = kt * ATILE + row * 128 + (((kin >> 3) ^ (row & 7)) << 4) +
                     ((kin & 7) << 1);
          *(unsigned short*)(smem + byte) = f2bf(v);
        }
      }
    }
    asm volatile("s_waitcnt lgkmcnt(0)" ::: "memory");  // own h-writes drained
#pragma unroll
    for (int m = 0; m < 2; ++m)
#pragma unroll
      for (int n = 0; n < 5; ++n) acc[m][n] = f32x4{0.f, 0.f, 0.f, 0.f};

    for (int tk = 0; tk < 5; ++tk) {
      __builtin_amdgcn_s_barrier();
      if (tk + 1 < 5) {
        stageB(Wt2, tk + 1, (tk + 1) & 1);
        asm volatile("s_waitcnt vmcnt(5)" ::: "memory");
      } else {
        asm volatile("s_waitcnt vmcnt(0)" ::: "memory");
      }
      __builtin_amdgcn_s_barrier();
      compute(smem + tk * ATILE, smem + AFULL + (tk & 1) * BBUF);
    }
  }

  if (!RO) {
    // ---- epilogue: acc -> LDS bounce -> coalesced dwordx4 stores ----
    const float* bp = FUSE2 ? bias2 : bias1;
    const bool relu = FUSE2 ? true : RELU1;
    __syncthreads();
    unsigned short* ep = (unsigned short*)smem;  // [64][EPITCH]
#pragma unroll
    for (int n = 0; n < 5; ++n) {
      int col = wc * 80 + n * 16 + cl;
      float bv = bp[col];
#pragma unroll
      for (int m = 0; m < 2; ++m) {
#pragma unroll
        for (int r = 0; r < 4; ++r) {
          int row = wr * 32 + m * 16 + q * 4 + r;
          float v = acc[m][n][r] + bv;
          if (relu) v = fmaxf(v, 0.f);
          ep[row * EPITCH + col] = f2bf(v);
        }
      }
    }
    __syncthreads();
    {
      const int row = t >> 3, c0 = (t & 7) * 40;  // 8 threads/row, 40 shorts
#pragma unroll
      for (int gch = 0; gch < 5; ++gch) {
        int col = c0 + gch * 8;
        bf16x8 v = *(const bf16x8*)(ep + row * EPITCH + col);
        size_t idx;
        if (TILED)
          idx = ((size_t)(col >> 6) * N_NODES + (bm + row)) * 64 + (col & 63);
        else
          idx = (size_t)(bm + row) * DP + col;
        *(bf16x8*)(C + idx) = v;
      }
    }
  } else {
    // ---- fused readout: relu(acc+bias1).Wro -> softmax -> graph bins ----
    float bv[5];
#pragma unroll
    for (int n = 0; n < 5; ++n) bv[n] = bias1[wc * 80 + n * 16 + cl];
#pragma unroll
    for (int m = 0; m < 2; ++m) {
#pragma unroll
      for (int r = 0; r < 4; ++r) {
        float s0 = 0.f, s1 = 0.f;
#pragma unroll
        for (int n = 0; n < 5; ++n) {
          int col = wc * 80 + n * 16 + cl;
          float v = fmaxf(acc[m][n][r] + bv[n], 0.f);
          s0 += v * wroL[2 * col];
          s1 += v * wroL[2 * col + 1];
        }
#pragma unroll
        for (int off = 1; off < 16; off <<= 1) {
          s0 += __shfl_xor(s0, off);
          s1 += __shfl_xor(s1, off);
        }
        if (cl == 0) {
          int row = wr * 32 + m * 16 + q * 4 + r;
          atomicAdd(&rowacc[2 * row], s0);
          atomicAdd(&rowacc[2 * row + 1], s1);
        }
      }
    }
    __syncthreads();
    if (t < 64) {
      float d0 = rowacc[2 * t] + bro[0];
      float d1 = rowacc[2 * t + 1] + bro[1];
      float mx = fmaxf(d0, d1);
      float e0 = expf(d0 - mx), e1 = expf(d1 - mx);
      float inv = 1.f / (e0 + e1);
      int g = gid[bm + t];
      atomicAdd(&binsL[2 * g], e0 * inv);
      atomicAdd(&binsL[2 * g + 1], e1 * inv);
    }
    __syncthreads();
    if (t < 2 * N_GRAPHS) {
      float v = binsL[t];
      if (v != 0.f) atomicAdd(&out[t], v);
    }
  }
}

// ================= CSR build =================
__global__ void hist_kernel(const int* __restrict__ dst, int* __restrict__ cnt) {
  int e = blockIdx.x * blockDim.x + threadIdx.x;
  if (e < N_EDGES) atomicAdd(&cnt[dst[e]], 1);
}

__global__ __launch_bounds__(256) void scan_kernel(
    const int* __restrict__ cnt, int* __restrict__ row_ptr, int* __restrict__ row_fill,
    float* __restrict__ out, int out_n) {
  if (threadIdx.x < out_n) out[threadIdx.x] = 0.f;  // zero d_out (fused)
  __shared__ int sums[256];
  const int t = threadIdx.x;
  const int base = t * 64;
  int loc[64];
#pragma unroll
  for (int i = 0; i < 16; ++i)
    *(int4*)&loc[i * 4] = *(const int4*)&cnt[base + i * 4];
  int s = 0;
#pragma unroll
  for (int i = 0; i < 64; ++i) s += loc[i];
  sums[t] = s;
  __syncthreads();
  for (int off = 1; off < 256; off <<= 1) {
    int x = (t >= off) ? sums[t - off] : 0;
    __syncthreads();
    sums[t] += x;
    __syncthreads();
  }
  int run = sums[t] - s;
  int rp[64];
#pragma unroll
  for (int i = 0; i < 64; ++i) {
    rp[i] = run;
    run += loc[i];
  }
#pragma unroll
  for (int i = 0; i < 16; ++i) {
    *(int4*)&row_ptr[base + i * 4] = *(const int4*)&rp[i * 4];
    *(int4*)&row_fill[base + i * 4] = *(const int4*)&rp[i * 4];
  }
  if (t == 255) row_ptr[N_NODES] = run;
}

__global__ void scatter_kernel(const int* __restrict__ src, const int* __restrict__ dst,
                               int* __restrict__ row_fill, int* __restrict__ csr_src) {
  int e = blockIdx.x * blockDim.x + threadIdx.x;
  if (e >= N_EDGES) return;
  int pos = atomicAdd(&row_fill[dst[e]], 1);
  csr_src[pos] = src[e];
}

// ========== SpMM aggregate: tiled gather, L2-resident per column phase ======
__global__ __launch_bounds__(256) void spmm_tiled(
    const unsigned short* __restrict__ Mt, const int* __restrict__ row_ptr,
    const int* __restrict__ csr_src, unsigned short* __restrict__ agg) {
  const int tile = blockIdx.y;
  const int wv = threadIdx.x >> 6;
  const int l = threadIdx.x & 63;
  const int g = l >> 3;    // node group
  const int cs = l & 7;    // 16B slot within 128B slice
  const int node = blockIdx.x * 32 + wv * 8 + g;
  const unsigned short* base = Mt + (size_t)tile * N_NODES * 64 + cs * 8;

  int j = row_ptr[node];
  const int j1 = row_ptr[node + 1];
  float acc[8] = {};
  for (; j + 8 <= j1; j += 8) {
    bf16x8 v[8];
#pragma unroll
    for (int u = 0; u < 8; ++u)
      v[u] = *(const bf16x8*)(base + (size_t)csr_src[j + u] * 64);
#pragma unroll
    for (int u = 0; u < 8; ++u)
#pragma unroll
      for (int i = 0; i < 8; ++i) acc[i] += bf2f(v[u][i]);
  }
  if (j + 4 <= j1) {
    bf16x8 v[4];
#pragma unroll
    for (int u = 0; u < 4; ++u)
      v[u] = *(const bf16x8*)(base + (size_t)csr_src[j + u] * 64);
#pragma unroll
    for (int u = 0; u < 4; ++u)
#pragma unroll
      for (int i = 0; i < 8; ++i) acc[i] += bf2f(v[u][i]);
    j += 4;
  }
  for (; j < j1; ++j) {
    bf16x8 v = *(const bf16x8*)(base + (size_t)csr_src[j] * 64);
#pragma unroll
    for (int i = 0; i < 8; ++i) acc[i] += bf2f(v[i]);
  }
  bf16x8 o;
#pragma unroll
  for (int i = 0; i < 8; ++i) o[i] = f2bf(acc[i]);
  *(bf16x8*)(agg + (size_t)node * DP + tile * 64 + cs * 8) = o;
}

// ===== prep: 7 weight transposes + 7 bias copies + cnt zero =====
// Wt slots 0..6 = Wlift_t, Wf1t, Wo1t, Wf2t, Wo2t, Wf3t, Wo3t (all [n][k]).
// biasP slots 0..6 = bl, bf1, bo1, bf2, bo2, bf3, bo3 (zero-padded to DP).
struct WPtrs {
  const float* W[7];
  const float* b[7];
};

__global__ __launch_bounds__(256) void prep_kernel(
    WPtrs p, unsigned short* __restrict__ Wt, float* __restrict__ biasP,
    int* __restrict__ cnt) {
  __shared__ unsigned short ld[64][33];
  const int t = threadIdx.x;
  const int wb = blockIdx.x;  // 0..349

  if (wb < 64) cnt[wb * 256 + t] = 0;  // zero hist counters (fused)

  const int wi = wb / 50;                // 0..6
  const int blk = wb - wi * 50;
  const int kt = blk / 5;                // 10 k-tiles of 32
  const int nt = blk - kt * 5;           // 5 n-tiles of 64
  const int k0 = kt * 32, n0 = nt * 64;
  const float* W = p.W[wi];

#pragma unroll
  for (int ps = 0; ps < 8; ++ps) {
    int idx = t + 256 * ps;
    int rr = idx >> 6, cc = idx & 63;     // rr: k in tile, cc: n in tile
    float v = (k0 + rr < GD && n0 + cc < GD) ? W[(size_t)(k0 + rr) * GD + n0 + cc] : 0.f;
    ld[cc][rr] = f2bf(v);
  }
  __syncthreads();
#pragma unroll
  for (int ps = 0; ps < 8; ++ps) {
    int idx = t + 256 * ps;
    int nn = idx >> 5, kk = idx & 31;
    Wt[(size_t)wi * WSZ + (size_t)(n0 + nn) * DP + k0 + kk] = ld[nn][kk];
  }
  if (blk == 0) {  // fused bias copy for this weight's bias
    for (int i = t; i < DP; i += 256)
      biasP[(size_t)wi * DP + i] = (i < GD) ? p.b[wi][i] : 0.f;
  }
}

// ================= host =================
extern "C" void kernel_launch(void* const* d_in, const int* in_sizes, int n_in,
                              void* d_out, int out_size, void* d_ws, size_t ws_size,
                              hipStream_t stream) {
  const float* node_feats = (const float*)d_in[0];
  const float* W_ro = (const float*)d_in[15];
  const float* b_ro = (const float*)d_in[16];
  const int* src = (const int*)d_in[17];
  const int* dst = (const int*)d_in[18];
  const int* gid = (const int*)d_in[19];
  float* out = (float*)d_out;

  WPtrs wp;
  wp.W[0] = (const float*)d_in[1];   wp.b[0] = (const float*)d_in[2];   // Wlift/bl
  wp.W[1] = (const float*)d_in[3];   wp.b[1] = (const float*)d_in[4];   // Wf1/bf1
  wp.W[2] = (const float*)d_in[5];   wp.b[2] = (const float*)d_in[6];   // Wo1/bo1
  wp.W[3] = (const float*)d_in[7];   wp.b[3] = (const float*)d_in[8];   // Wf2/bf2
  wp.W[4] = (const float*)d_in[9];   wp.b[4] = (const float*)d_in[10];  // Wo2/bo2
  wp.W[5] = (const float*)d_in[11];  wp.b[5] = (const float*)d_in[12];  // Wf3/bf3
  wp.W[6] = (const float*)d_in[13];  wp.b[6] = (const float*)d_in[14];  // Wo3/bo3

  char* p = (char*)d_ws;
  unsigned short* X = (unsigned short*)p;  p += (size_t)N_NODES * DP * 2;
  unsigned short* Y = (unsigned short*)p;  p += (size_t)N_NODES * DP * 2;
  unsigned short* Wt = (unsigned short*)p; p += (size_t)7 * WSZ * 2;
  float* biasP = (float*)p;                p += 7 * DP * 4;
  int* cnt = (int*)p;                      p += N_NODES * 4;
  int* row_ptr = (int*)p;                  p += (N_NODES + 16) * 4;
  int* row_fill = (int*)p;                 p += N_NODES * 4;
  int* csr_src = (int*)p;                  p += N_EDGES * 4;

  // --- prep (weights + biases + cnt zero) + CSR build ---
  prep_kernel<<<350, 256, 0, stream>>>(wp, Wt, biasP, cnt);
  hist_kernel<<<N_EDGES / 256, 256, 0, stream>>>(dst, cnt);
  scan_kernel<<<1, 256, 0, stream>>>(cnt, row_ptr, row_fill, out, out_size);
  scatter_kernel<<<N_EDGES / 256, 256, 0, stream>>>(src, dst, row_fill, csr_src);

  dim3 sgrid(N_NODES / 32, NTILE);  // (512, 5)

  // G1 (lift fused): h0 = feats@Wl+bl (no relu); msg1 = relu(h0@Wf1+bf1) [tiled]
  gemm_f<false, true, true, false, true><<<256, 512, 0, stream>>>(
      nullptr, node_feats, Wt + 0 * WSZ, biasP + 0 * DP,
      Wt + 1 * WSZ, biasP + 1 * DP, Y, nullptr, nullptr, nullptr, nullptr);
  spmm_tiled<<<sgrid, 256, 0, stream>>>(Y, row_ptr, csr_src, X);
  // F2: h1 = relu(agg1@Wo1+bo1) in LDS; msg2 = relu(h1@Wf2+bf2) [tiled]
  gemm_f<true, true, true, false, false><<<256, 512, 0, stream>>>(
      X, nullptr, Wt + 2 * WSZ, biasP + 2 * DP,
      Wt + 3 * WSZ, biasP + 3 * DP, Y, nullptr, nullptr, nullptr, nullptr);
  spmm_tiled<<<sgrid, 256, 0, stream>>>(Y, row_ptr, csr_src, X);
  // F3: h2 -> msg3 [tiled]
  gemm_f<true, true, true, false, false><<<256, 512, 0, stream>>>(
      X, nullptr, Wt + 4 * WSZ, biasP + 4 * DP,
      Wt + 5 * WSZ, biasP + 5 * DP, Y, nullptr, nullptr, nullptr, nullptr);
  spmm_tiled<<<sgrid, 256, 0, stream>>>(Y, row_ptr, csr_src, X);
  // G4: h3 = relu(agg3@Wo3+bo3) + fused readout
  gemm_f<true, false, false, true, false><<<256, 512, 0, stream>>>(
      X, nullptr, Wt + 6 * WSZ, biasP + 6 * DP, nullptr, nullptr, nullptr,
      W_ro, b_ro, gid, out);
}

// Round 17
// 160.344 us; speedup vs baseline: 1.1093x; 1.1093x over previous
//
#include <hip/hip_runtime.h>
#include <hip/hip_bf16.h>

#define N_NODES 16384
#define N_EDGES 262144
#define GD 300        // real feature dim
#define DP 320        // padded feature dim (pads are exact zeros)
#define N_GRAPHS 64
#define NTILE 5       // 5 column tiles of 64
#define CAP 96        // padded adjacency capacity (mean deg 16, P(>96)<1e-40)

typedef short bf16x8 __attribute__((ext_vector_type(8)));
typedef float f32x4 __attribute__((ext_vector_type(4)));

__device__ static inline unsigned short f2bf(float v) {
  __hip_bfloat16 b = __float2bfloat16(v);
  return __builtin_bit_cast(unsigned short, b);
}
__device__ static inline float bf2f(unsigned short u) {
  return __bfloat162float(__builtin_bit_cast(__hip_bfloat16, u));
}

#define GLOAD_LDS16(g, l)                                                    \
  __builtin_amdgcn_global_load_lds(                                          \
      (const __attribute__((address_space(1))) void*)(g),                    \
      (__attribute__((address_space(3))) void*)(l), 16, 0, 0)

// ============== fused two-stage bf16 MFMA GEMM (R12 structure) ==============
// Stage 1: C1 = act1(A @ W1 + b1); A staged once in LDS (gload_lds or CONVF
//          fp32-convert). act1 = relu iff RELU1 (lift fusion needs identity).
// FUSE2:   h=C1 kept in LDS (staged-A layout) -> C = relu(h @ W2 + b2)
// RO:      no C; fused readout d = relu(C1+b1).Wro -> softmax -> graph bins
// BM=64 rows/block, BN=320 (full width), 512 thr = 8 waves (2 row x 4 col),
// per-wave 2x5 frags of 16x16x32. B double-buffered 2x40KB, counted
// s_waitcnt vmcnt(5) across raw barriers (R12-verified pipeline).
// LDS rows 128B, 16B-slot s holds global slot s^(row&7) (conflict-free b128).
constexpr int ATILE = 8192;                  // one 64-row x 64-k A tile
constexpr int AFULL = 5 * ATILE;             // 40960
constexpr int BBUF = 40960;                  // one 320-row x 64-k B tile
constexpr int EPITCH = 328;                  // bounce pitch (>= BN=320!)
constexpr size_t WSZ = (size_t)DP * DP;
static_assert(64 * EPITCH * 2 <= AFULL + 2 * BBUF, "epilogue bounce fits");

template <bool RELU1, bool TILED, bool FUSE2, bool RO, bool CONVF>
__global__ __launch_bounds__(512, 2) void gemm_f(
    const unsigned short* __restrict__ A, const float* __restrict__ nf,
    const unsigned short* __restrict__ Wt1,
    const float* __restrict__ bias1, const unsigned short* __restrict__ Wt2,
    const float* __restrict__ bias2, unsigned short* __restrict__ C,
    const float* __restrict__ Wro, const float* __restrict__ bro,
    const int* __restrict__ gid, float* __restrict__ out) {
  __shared__ __align__(16) char smem[AFULL + 2 * BBUF];  // 122880 B
  __shared__ float wroL[2 * DP];
  __shared__ float rowacc[2 * 64];
  __shared__ float binsL[2 * N_GRAPHS];

  const int bm = blockIdx.x * 64;
  const int t = threadIdx.x;
  const int w = t >> 6, l = t & 63;
  const int wr = w & 1;        // row group: rows wr*32..+31
  const int wc = w >> 1;       // col group 0..3: cols wc*80..+79
  const int cl = l & 15, q = l >> 4;
  const int lr = l >> 3;             // row within 8-row staging group
  const int sg = (l & 7) ^ lr;       // pre-swizzled global 16B slot

  if (RO) {
    for (int i = t; i < DP; i += 512) {
      wroL[2 * i] = (i < GD) ? Wro[2 * i] : 0.f;
      wroL[2 * i + 1] = (i < GD) ? Wro[2 * i + 1] : 0.f;
    }
    if (t < 128) rowacc[t] = 0.f;
    if (t < 2 * N_GRAPHS) binsL[t] = 0.f;
  }

  auto stageB = [&](const unsigned short* W, int tk, int buf) {
    char* lb = smem + AFULL + buf * BBUF;
#pragma unroll
    for (int i = 0; i < 5; ++i) {
      int c = w + 8 * i;  // 1KB chunk = 8 rows
      GLOAD_LDS16(W + (size_t)(c * 8 + lr) * DP + tk * 64 + 8 * sg,
                  lb + c * 1024);
    }
  };

  f32x4 acc[2][5] = {};

  auto compute = [&](const char* lA, const char* lB) {
#pragma unroll
    for (int ks = 0; ks < 2; ++ks) {
      bf16x8 a[2], b[5];
#pragma unroll
      for (int m = 0; m < 2; ++m) {
        int r = wr * 32 + m * 16 + cl;
        int slot = (ks * 4 + q) ^ (r & 7);
        a[m] = *(const bf16x8*)(lA + r * 128 + slot * 16);
      }
#pragma unroll
      for (int n = 0; n < 5; ++n) {
        int r = wc * 80 + n * 16 + cl;
        int slot = (ks * 4 + q) ^ (r & 7);
        b[n] = *(const bf16x8*)(lB + r * 128 + slot * 16);
      }
#pragma unroll
      for (int m = 0; m < 2; ++m)
#pragma unroll
        for (int n = 0; n < 5; ++n)
          acc[m][n] = __builtin_amdgcn_mfma_f32_16x16x32_bf16(a[m], b[n],
                                                              acc[m][n], 0, 0, 0);
    }
  };

  // ---- prologue: B tile 0 first (loads in flight), then stage A ----
  stageB(Wt1, 0, 0);
  if (CONVF) {
    // A from fp32 node_feats: reg-load + convert + ds_write into XOR layout.
    const int r = t >> 3;       // 0..63 (8 threads per row)
    const int ls = t & 7;       // 16B slot within each 128B k-tile
    const float* rp = nf + (size_t)(bm + r) * GD;
#pragma unroll
    for (int p = 0; p < 5; ++p) {
      int c0 = p * 64 + ls * 8;
      bf16x8 o;
      if (c0 + 8 <= GD) {
        float4 a = *(const float4*)(rp + c0);
        float4 b = *(const float4*)(rp + c0 + 4);
        o[0] = f2bf(a.x); o[1] = f2bf(a.y); o[2] = f2bf(a.z); o[3] = f2bf(a.w);
        o[4] = f2bf(b.x); o[5] = f2bf(b.y); o[6] = f2bf(b.z); o[7] = f2bf(b.w);
      } else {
#pragma unroll
        for (int i = 0; i < 8; ++i) {
          int c = c0 + i;
          o[i] = f2bf(c < GD ? rp[c] : 0.f);  // pads MUST be exact zeros
        }
      }
      *(bf16x8*)(smem + p * ATILE + r * 128 + ((ls ^ (r & 7)) << 4)) = o;
    }
    asm volatile("s_waitcnt lgkmcnt(0)" ::: "memory");
  } else {
#pragma unroll
    for (int p = 0; p < 5; ++p)
      GLOAD_LDS16(A + (size_t)(bm + w * 8 + lr) * DP + p * 64 + 8 * sg,
                  smem + p * ATILE + w * 1024);
  }

  // ---- stage-1 K loop (R12-verified: counted vmcnt across raw barriers) ----
  for (int tk = 0; tk < 5; ++tk) {
    __builtin_amdgcn_s_barrier();
    if (tk + 1 < 5) {
      stageB(Wt1, tk + 1, (tk + 1) & 1);
      asm volatile("s_waitcnt vmcnt(5)" ::: "memory");
    } else {
      asm volatile("s_waitcnt vmcnt(0)" ::: "memory");
    }
    __builtin_amdgcn_s_barrier();
    compute(smem + tk * ATILE, smem + AFULL + (tk & 1) * BBUF);
  }

  if (FUSE2) {
    // ---- h = act1(acc + bias1) -> LDS (staged-A layout), then stage 2 ----
    __syncthreads();          // all waves done with A region and Bbuf0
    stageB(Wt2, 0, 0);        // W2 tile 0 in flight during h write
#pragma unroll
    for (int n = 0; n < 5; ++n) {
      int col = wc * 80 + n * 16 + cl;
      float bv = bias1[col];
      int kt = col >> 6, kin = col & 63;
#pragma unroll
      for (int m = 0; m < 2; ++m) {
#pragma unroll
        for (int r = 0; r < 4; ++r) {
          int row = wr * 32 + m * 16 + q * 4 + r;
          float v = acc[m][n][r] + bv;
          if (RELU1) v = fmaxf(v, 0.f);   // lift fusion: RELU1=false
          int byte = kt * ATILE + row * 128 + (((kin >> 3) ^ (row & 7)) << 4) +
                     ((kin & 7) << 1);
          *(unsigned short*)(smem + byte) = f2bf(v);
        }
      }
    }
    asm volatile("s_waitcnt lgkmcnt(0)" ::: "memory");  // own h-writes drained
#pragma unroll
    for (int m = 0; m < 2; ++m)
#pragma unroll
      for (int n = 0; n < 5; ++n) acc[m][n] = f32x4{0.f, 0.f, 0.f, 0.f};

    for (int tk = 0; tk < 5; ++tk) {
      __builtin_amdgcn_s_barrier();
      if (tk + 1 < 5) {
        stageB(Wt2, tk + 1, (tk + 1) & 1);
        asm volatile("s_waitcnt vmcnt(5)" ::: "memory");
      } else {
        asm volatile("s_waitcnt vmcnt(0)" ::: "memory");
      }
      __builtin_amdgcn_s_barrier();
      compute(smem + tk * ATILE, smem + AFULL + (tk & 1) * BBUF);
    }
  }

  if (!RO) {
    // ---- epilogue: acc -> LDS bounce -> coalesced dwordx4 stores ----
    const float* bp = FUSE2 ? bias2 : bias1;
    const bool relu = FUSE2 ? true : RELU1;
    __syncthreads();
    unsigned short* ep = (unsigned short*)smem;  // [64][EPITCH]
#pragma unroll
    for (int n = 0; n < 5; ++n) {
      int col = wc * 80 + n * 16 + cl;
      float bv = bp[col];
#pragma unroll
      for (int m = 0; m < 2; ++m) {
#pragma unroll
        for (int r = 0; r < 4; ++r) {
          int row = wr * 32 + m * 16 + q * 4 + r;
          float v = acc[m][n][r] + bv;
          if (relu) v = fmaxf(v, 0.f);
          ep[row * EPITCH + col] = f2bf(v);
        }
      }
    }
    __syncthreads();
    {
      const int row = t >> 3, c0 = (t & 7) * 40;  // 8 threads/row, 40 shorts
#pragma unroll
      for (int gch = 0; gch < 5; ++gch) {
        int col = c0 + gch * 8;
        bf16x8 v = *(const bf16x8*)(ep + row * EPITCH + col);
        size_t idx;
        if (TILED)
          idx = ((size_t)(col >> 6) * N_NODES + (bm + row)) * 64 + (col & 63);
        else
          idx = (size_t)(bm + row) * DP + col;
        *(bf16x8*)(C + idx) = v;
      }
    }
  } else {
    // ---- fused readout: relu(acc+bias1).Wro -> softmax -> graph bins ----
    float bv[5];
#pragma unroll
    for (int n = 0; n < 5; ++n) bv[n] = bias1[wc * 80 + n * 16 + cl];
#pragma unroll
    for (int m = 0; m < 2; ++m) {
#pragma unroll
      for (int r = 0; r < 4; ++r) {
        float s0 = 0.f, s1 = 0.f;
#pragma unroll
        for (int n = 0; n < 5; ++n) {
          int col = wc * 80 + n * 16 + cl;
          float v = fmaxf(acc[m][n][r] + bv[n], 0.f);
          s0 += v * wroL[2 * col];
          s1 += v * wroL[2 * col + 1];
        }
#pragma unroll
        for (int off = 1; off < 16; off <<= 1) {
          s0 += __shfl_xor(s0, off);
          s1 += __shfl_xor(s1, off);
        }
        if (cl == 0) {
          int row = wr * 32 + m * 16 + q * 4 + r;
          atomicAdd(&rowacc[2 * row], s0);
          atomicAdd(&rowacc[2 * row + 1], s1);
        }
      }
    }
    __syncthreads();
    if (t < 64) {
      float d0 = rowacc[2 * t] + bro[0];
      float d1 = rowacc[2 * t + 1] + bro[1];
      float mx = fmaxf(d0, d1);
      float e0 = expf(d0 - mx), e1 = expf(d1 - mx);
      float inv = 1.f / (e0 + e1);
      int g = gid[bm + t];
      atomicAdd(&binsL[2 * g], e0 * inv);
      atomicAdd(&binsL[2 * g + 1], e1 * inv);
    }
    __syncthreads();
    if (t < 2 * N_GRAPHS) {
      float v = binsL[t];
      if (v != 0.f) atomicAdd(&out[t], v);
    }
  }
}

// ===== padded adjacency build: one pass, no scan =====
// pad[d*CAP + pos] = src for pos = atomicAdd(cnt[d],1).  cnt pre-zeroed by
// memset.  Block 0 also zeroes d_out (needed each call; G4 accumulates).
__global__ void scatter_pad(const int* __restrict__ src, const int* __restrict__ dst,
                            int* __restrict__ cnt, int* __restrict__ pad,
                            float* __restrict__ out, int out_n) {
  if (blockIdx.x == 0 && threadIdx.x < out_n) out[threadIdx.x] = 0.f;
  int e = blockIdx.x * blockDim.x + threadIdx.x;
  if (e >= N_EDGES) return;
  int d = dst[e];
  int pos = atomicAdd(&cnt[d], 1);
  if (pos < CAP) pad[(size_t)d * CAP + pos] = src[e];
}

// ========== SpMM aggregate: tiled gather, L2-resident per column phase ======
__global__ __launch_bounds__(256) void spmm_tiled(
    const unsigned short* __restrict__ Mt, const int* __restrict__ cnt,
    const int* __restrict__ pad, unsigned short* __restrict__ agg) {
  const int tile = blockIdx.y;
  const int wv = threadIdx.x >> 6;
  const int l = threadIdx.x & 63;
  const int g = l >> 3;    // node group
  const int cs = l & 7;    // 16B slot within 128B slice
  const int node = blockIdx.x * 32 + wv * 8 + g;
  const unsigned short* base = Mt + (size_t)tile * N_NODES * 64 + cs * 8;
  const int* lst = pad + (size_t)node * CAP;

  const int j1 = min(cnt[node], CAP);
  int j = 0;
  float acc[8] = {};
  for (; j + 8 <= j1; j += 8) {
    bf16x8 v[8];
#pragma unroll
    for (int u = 0; u < 8; ++u)
      v[u] = *(const bf16x8*)(base + (size_t)lst[j + u] * 64);
#pragma unroll
    for (int u = 0; u < 8; ++u)
#pragma unroll
      for (int i = 0; i < 8; ++i) acc[i] += bf2f(v[u][i]);
  }
  if (j + 4 <= j1) {
    bf16x8 v[4];
#pragma unroll
    for (int u = 0; u < 4; ++u)
      v[u] = *(const bf16x8*)(base + (size_t)lst[j + u] * 64);
#pragma unroll
    for (int u = 0; u < 4; ++u)
#pragma unroll
      for (int i = 0; i < 8; ++i) acc[i] += bf2f(v[u][i]);
    j += 4;
  }
  for (; j < j1; ++j) {
    bf16x8 v = *(const bf16x8*)(base + (size_t)lst[j] * 64);
#pragma unroll
    for (int i = 0; i < 8; ++i) acc[i] += bf2f(v[i]);
  }
  bf16x8 o;
#pragma unroll
  for (int i = 0; i < 8; ++i) o[i] = f2bf(acc[i]);
  *(bf16x8*)(agg + (size_t)node * DP + tile * 64 + cs * 8) = o;
}

// ===== prep: 7 weight transposes + 7 bias copies =====
// Wt slots 0..6 = Wlift_t, Wf1t, Wo1t, Wf2t, Wo2t, Wf3t, Wo3t (all [n][k]).
// biasP slots 0..6 = bl, bf1, bo1, bf2, bo2, bf3, bo3 (zero-padded to DP).
struct WPtrs {
  const float* W[7];
  const float* b[7];
};

__global__ __launch_bounds__(256) void prep_kernel(
    WPtrs p, unsigned short* __restrict__ Wt, float* __restrict__ biasP) {
  __shared__ unsigned short ld[64][33];
  const int t = threadIdx.x;
  const int wb = blockIdx.x;  // 0..349

  const int wi = wb / 50;                // 0..6
  const int blk = wb - wi * 50;
  const int kt = blk / 5;                // 10 k-tiles of 32
  const int nt = blk - kt * 5;           // 5 n-tiles of 64
  const int k0 = kt * 32, n0 = nt * 64;
  const float* W = p.W[wi];

#pragma unroll
  for (int ps = 0; ps < 8; ++ps) {
    int idx = t + 256 * ps;
    int rr = idx >> 6, cc = idx & 63;     // rr: k in tile, cc: n in tile
    float v = (k0 + rr < GD && n0 + cc < GD) ? W[(size_t)(k0 + rr) * GD + n0 + cc] : 0.f;
    ld[cc][rr] = f2bf(v);
  }
  __syncthreads();
#pragma unroll
  for (int ps = 0; ps < 8; ++ps) {
    int idx = t + 256 * ps;
    int nn = idx >> 5, kk = idx & 31;
    Wt[(size_t)wi * WSZ + (size_t)(n0 + nn) * DP + k0 + kk] = ld[nn][kk];
  }
  if (blk == 0) {  // fused bias copy for this weight's bias
    for (int i = t; i < DP; i += 256)
      biasP[(size_t)wi * DP + i] = (i < GD) ? p.b[wi][i] : 0.f;
  }
}

// ================= host =================
extern "C" void kernel_launch(void* const* d_in, const int* in_sizes, int n_in,
                              void* d_out, int out_size, void* d_ws, size_t ws_size,
                              hipStream_t stream) {
  const float* node_feats = (const float*)d_in[0];
  const float* W_ro = (const float*)d_in[15];
  const float* b_ro = (const float*)d_in[16];
  const int* src = (const int*)d_in[17];
  const int* dst = (const int*)d_in[18];
  const int* gid = (const int*)d_in[19];
  float* out = (float*)d_out;

  WPtrs wp;
  wp.W[0] = (const float*)d_in[1];   wp.b[0] = (const float*)d_in[2];   // Wlift/bl
  wp.W[1] = (const float*)d_in[3];   wp.b[1] = (const float*)d_in[4];   // Wf1/bf1
  wp.W[2] = (const float*)d_in[5];   wp.b[2] = (const float*)d_in[6];   // Wo1/bo1
  wp.W[3] = (const float*)d_in[7];   wp.b[3] = (const float*)d_in[8];   // Wf2/bf2
  wp.W[4] = (const float*)d_in[9];   wp.b[4] = (const float*)d_in[10];  // Wo2/bo2
  wp.W[5] = (const float*)d_in[11];  wp.b[5] = (const float*)d_in[12];  // Wf3/bf3
  wp.W[6] = (const float*)d_in[13];  wp.b[6] = (const float*)d_in[14];  // Wo3/bo3

  char* p = (char*)d_ws;
  unsigned short* X = (unsigned short*)p;  p += (size_t)N_NODES * DP * 2;
  unsigned short* Y = (unsigned short*)p;  p += (size_t)N_NODES * DP * 2;
  unsigned short* Wt = (unsigned short*)p; p += (size_t)7 * WSZ * 2;
  float* biasP = (float*)p;                p += 7 * DP * 4;
  int* cnt = (int*)p;                      p += N_NODES * 4;
  int* pad = (int*)p;                      p += (size_t)N_NODES * CAP * 4;

  // --- adjacency (one-pass padded) + weight prep ---
  hipMemsetAsync(cnt, 0, N_NODES * sizeof(int), stream);
  scatter_pad<<<N_EDGES / 256, 256, 0, stream>>>(src, dst, cnt, pad, out, out_size);
  prep_kernel<<<350, 256, 0, stream>>>(wp, Wt, biasP);

  dim3 sgrid(N_NODES / 32, NTILE);  // (512, 5)

  // G1 (lift fused): h0 = feats@Wl+bl (no relu); msg1 = relu(h0@Wf1+bf1) [tiled]
  gemm_f<false, true, true, false, true><<<256, 512, 0, stream>>>(
      nullptr, node_feats, Wt + 0 * WSZ, biasP + 0 * DP,
      Wt + 1 * WSZ, biasP + 1 * DP, Y, nullptr, nullptr, nullptr, nullptr);
  spmm_tiled<<<sgrid, 256, 0, stream>>>(Y, cnt, pad, X);
  // F2: h1 = relu(agg1@Wo1+bo1) in LDS; msg2 = relu(h1@Wf2+bf2) [tiled]
  gemm_f<true, true, true, false, false><<<256, 512, 0, stream>>>(
      X, nullptr, Wt + 2 * WSZ, biasP + 2 * DP,
      Wt + 3 * WSZ, biasP + 3 * DP, Y, nullptr, nullptr, nullptr, nullptr);
  spmm_tiled<<<sgrid, 256, 0, stream>>>(Y, cnt, pad, X);
  // F3: h2 -> msg3 [tiled]
  gemm_f<true, true, true, false, false><<<256, 512, 0, stream>>>(
      X, nullptr, Wt + 4 * WSZ, biasP + 4 * DP,
      Wt + 5 * WSZ, biasP + 5 * DP, Y, nullptr, nullptr, nullptr, nullptr);
  spmm_tiled<<<sgrid, 256, 0, stream>>>(Y, cnt, pad, X);
  // G4: h3 = relu(agg3@Wo3+bo3) + fused readout
  gemm_f<true, false, false, true, false><<<256, 512, 0, stream>>>(
      X, nullptr, Wt + 6 * WSZ, biasP + 6 * DP, nullptr, nullptr, nullptr,
      W_ro, b_ro, gid, out);
}

// Round 18
// 154.869 us; speedup vs baseline: 1.1485x; 1.0354x over previous
//
#include <hip/hip_runtime.h>
#include <hip/hip_bf16.h>

#define N_NODES 16384
#define N_EDGES 262144
#define GD 300        // real feature dim
#define DP 320        // padded feature dim (pads are exact zeros)
#define N_GRAPHS 64
#define NTILE 5       // 5 column tiles of 64
#define CAP 96        // padded adjacency capacity (mean deg 16, P(>96)<1e-40)

typedef short bf16x8 __attribute__((ext_vector_type(8)));
typedef float f32x4 __attribute__((ext_vector_type(4)));

__device__ static inline unsigned short f2bf(float v) {
  __hip_bfloat16 b = __float2bfloat16(v);
  return __builtin_bit_cast(unsigned short, b);
}
__device__ static inline float bf2f(unsigned short u) {
  return __bfloat162float(__builtin_bit_cast(__hip_bfloat16, u));
}

#define GLOAD_LDS16(g, l)                                                    \
  __builtin_amdgcn_global_load_lds(                                          \
      (const __attribute__((address_space(1))) void*)(g),                    \
      (__attribute__((address_space(3))) void*)(l), 16, 0, 0)

// ============== fused two-stage bf16 MFMA GEMM (R12 structure) ==============
// Stage 1: C1 = act1(A @ W1 + b1); A staged once in LDS (gload_lds or CONVF
//          fp32-convert). act1 = relu iff RELU1 (lift fusion needs identity).
// FUSE2:   h=C1 kept in LDS (staged-A layout) -> C = relu(h @ W2 + b2).
//          Stage-2 B tile 0 is PREFETCHED into buf1 during stage-1's last
//          K-tile (buf1 provably free after that iteration's leading barrier)
//          -> no vmcnt(0) drain at the stage seam; stage-2 tile tk lives in
//          buf (tk+1)&1.
// RO:      no C; fused readout d = relu(C1+b1).Wro -> softmax -> graph bins
// BM=64 rows/block, BN=320 (full width), 512 thr = 8 waves (2 row x 4 col),
// per-wave 2x5 frags of 16x16x32. B double-buffered 2x40KB, counted
// s_waitcnt vmcnt(5) across raw barriers (R12-verified pipeline).
// LDS rows 128B, 16B-slot s holds global slot s^(row&7) (conflict-free b128).
constexpr int ATILE = 8192;                  // one 64-row x 64-k A tile
constexpr int AFULL = 5 * ATILE;             // 40960
constexpr int BBUF = 40960;                  // one 320-row x 64-k B tile
constexpr int EPITCH = 328;                  // bounce pitch (>= BN=320!)
constexpr size_t WSZ = (size_t)DP * DP;
static_assert(64 * EPITCH * 2 <= AFULL + 2 * BBUF, "epilogue bounce fits");

template <bool RELU1, bool TILED, bool FUSE2, bool RO, bool CONVF>
__global__ __launch_bounds__(512, 2) void gemm_f(
    const unsigned short* __restrict__ A, const float* __restrict__ nf,
    const unsigned short* __restrict__ Wt1,
    const float* __restrict__ bias1, const unsigned short* __restrict__ Wt2,
    const float* __restrict__ bias2, unsigned short* __restrict__ C,
    const float* __restrict__ Wro, const float* __restrict__ bro,
    const int* __restrict__ gid, float* __restrict__ out) {
  __shared__ __align__(16) char smem[AFULL + 2 * BBUF];  // 122880 B
  __shared__ float wroL[2 * DP];
  __shared__ float rowacc[2 * 64];
  __shared__ float binsL[2 * N_GRAPHS];

  const int bm = blockIdx.x * 64;
  const int t = threadIdx.x;
  const int w = t >> 6, l = t & 63;
  const int wr = w & 1;        // row group: rows wr*32..+31
  const int wc = w >> 1;       // col group 0..3: cols wc*80..+79
  const int cl = l & 15, q = l >> 4;
  const int lr = l >> 3;             // row within 8-row staging group
  const int sg = (l & 7) ^ lr;       // pre-swizzled global 16B slot

  if (RO) {
    for (int i = t; i < DP; i += 512) {
      wroL[2 * i] = (i < GD) ? Wro[2 * i] : 0.f;
      wroL[2 * i + 1] = (i < GD) ? Wro[2 * i + 1] : 0.f;
    }
    if (t < 128) rowacc[t] = 0.f;
    if (t < 2 * N_GRAPHS) binsL[t] = 0.f;
  }

  auto stageB = [&](const unsigned short* W, int tk, int buf) {
    char* lb = smem + AFULL + buf * BBUF;
#pragma unroll
    for (int i = 0; i < 5; ++i) {
      int c = w + 8 * i;  // 1KB chunk = 8 rows
      GLOAD_LDS16(W + (size_t)(c * 8 + lr) * DP + tk * 64 + 8 * sg,
                  lb + c * 1024);
    }
  };

  f32x4 acc[2][5] = {};

  auto compute = [&](const char* lA, const char* lB) {
#pragma unroll
    for (int ks = 0; ks < 2; ++ks) {
      bf16x8 a[2], b[5];
#pragma unroll
      for (int m = 0; m < 2; ++m) {
        int r = wr * 32 + m * 16 + cl;
        int slot = (ks * 4 + q) ^ (r & 7);
        a[m] = *(const bf16x8*)(lA + r * 128 + slot * 16);
      }
#pragma unroll
      for (int n = 0; n < 5; ++n) {
        int r = wc * 80 + n * 16 + cl;
        int slot = (ks * 4 + q) ^ (r & 7);
        b[n] = *(const bf16x8*)(lB + r * 128 + slot * 16);
      }
#pragma unroll
      for (int m = 0; m < 2; ++m)
#pragma unroll
        for (int n = 0; n < 5; ++n)
          acc[m][n] = __builtin_amdgcn_mfma_f32_16x16x32_bf16(a[m], b[n],
                                                              acc[m][n], 0, 0, 0);
    }
  };

  // ---- prologue: B tile 0 first (loads in flight), then stage A ----
  stageB(Wt1, 0, 0);
  if (CONVF) {
    // A from fp32 node_feats: reg-load + convert + ds_write into XOR layout.
    const int r = t >> 3;       // 0..63 (8 threads per row)
    const int ls = t & 7;       // 16B slot within each 128B k-tile
    const float* rp = nf + (size_t)(bm + r) * GD;
#pragma unroll
    for (int p = 0; p < 5; ++p) {
      int c0 = p * 64 + ls * 8;
      bf16x8 o;
      if (c0 + 8 <= GD) {
        float4 a = *(const float4*)(rp + c0);
        float4 b = *(const float4*)(rp + c0 + 4);
        o[0] = f2bf(a.x); o[1] = f2bf(a.y); o[2] = f2bf(a.z); o[3] = f2bf(a.w);
        o[4] = f2bf(b.x); o[5] = f2bf(b.y); o[6] = f2bf(b.z); o[7] = f2bf(b.w);
      } else {
#pragma unroll
        for (int i = 0; i < 8; ++i) {
          int c = c0 + i;
          o[i] = f2bf(c < GD ? rp[c] : 0.f);  // pads MUST be exact zeros
        }
      }
      *(bf16x8*)(smem + p * ATILE + r * 128 + ((ls ^ (r & 7)) << 4)) = o;
    }
    asm volatile("s_waitcnt lgkmcnt(0)" ::: "memory");
  } else {
#pragma unroll
    for (int p = 0; p < 5; ++p)
      GLOAD_LDS16(A + (size_t)(bm + w * 8 + lr) * DP + p * 64 + 8 * sg,
                  smem + p * ATILE + w * 1024);
  }

  // ---- stage-1 K loop (counted vmcnt across raw barriers) ----
  for (int tk = 0; tk < 5; ++tk) {
    __builtin_amdgcn_s_barrier();
    if (tk + 1 < 5) {
      stageB(Wt1, tk + 1, (tk + 1) & 1);
      asm volatile("s_waitcnt vmcnt(5)" ::: "memory");
    } else if (FUSE2) {
      // prefetch stage-2 tile 0 into buf1 (free since compute(3) done);
      // counted wait covers stage-1 tile 4 only.
      stageB(Wt2, 0, 1);
      asm volatile("s_waitcnt vmcnt(5)" ::: "memory");
    } else {
      asm volatile("s_waitcnt vmcnt(0)" ::: "memory");
    }
    __builtin_amdgcn_s_barrier();
    compute(smem + tk * ATILE, smem + AFULL + (tk & 1) * BBUF);
  }

  if (FUSE2) {
    // ---- h = act1(acc + bias1) -> LDS (staged-A layout), then stage 2 ----
    __syncthreads();          // all waves done reading A region
#pragma unroll
    for (int n = 0; n < 5; ++n) {
      int col = wc * 80 + n * 16 + cl;
      float bv = bias1[col];
      int kt = col >> 6, kin = col & 63;
#pragma unroll
      for (int m = 0; m < 2; ++m) {
#pragma unroll
        for (int r = 0; r < 4; ++r) {
          int row = wr * 32 + m * 16 + q * 4 + r;
          float v = acc[m][n][r] + bv;
          if (RELU1) v = fmaxf(v, 0.f);   // lift fusion: RELU1=false
          int byte = kt * ATILE + row * 128 + (((kin >> 3) ^ (row & 7)) << 4) +
                     ((kin & 7) << 1);
          *(unsigned short*)(smem + byte) = f2bf(v);
        }
      }
    }
    asm volatile("s_waitcnt lgkmcnt(0)" ::: "memory");  // own h-writes drained
#pragma unroll
    for (int m = 0; m < 2; ++m)
#pragma unroll
      for (int n = 0; n < 5; ++n) acc[m][n] = f32x4{0.f, 0.f, 0.f, 0.f};

    // stage-2: tile tk lives in buf (tk+1)&1 (tile 0 prefetched in buf1)
    for (int tk = 0; tk < 5; ++tk) {
      __builtin_amdgcn_s_barrier();
      if (tk + 1 < 5) {
        stageB(Wt2, tk + 1, tk & 1);
        asm volatile("s_waitcnt vmcnt(5)" ::: "memory");
      } else {
        asm volatile("s_waitcnt vmcnt(0)" ::: "memory");
      }
      __builtin_amdgcn_s_barrier();
      compute(smem + tk * ATILE, smem + AFULL + ((tk + 1) & 1) * BBUF);
    }
  }

  if (!RO) {
    // ---- epilogue: acc -> LDS bounce -> coalesced dwordx4 stores ----
    const float* bp = FUSE2 ? bias2 : bias1;
    const bool relu = FUSE2 ? true : RELU1;
    __syncthreads();
    unsigned short* ep = (unsigned short*)smem;  // [64][EPITCH]
#pragma unroll
    for (int n = 0; n < 5; ++n) {
      int col = wc * 80 + n * 16 + cl;
      float bv = bp[col];
#pragma unroll
      for (int m = 0; m < 2; ++m) {
#pragma unroll
        for (int r = 0; r < 4; ++r) {
          int row = wr * 32 + m * 16 + q * 4 + r;
          float v = acc[m][n][r] + bv;
          if (relu) v = fmaxf(v, 0.f);
          ep[row * EPITCH + col] = f2bf(v);
        }
      }
    }
    __syncthreads();
    {
      const int row = t >> 3, c0 = (t & 7) * 40;  // 8 threads/row, 40 shorts
#pragma unroll
      for (int gch = 0; gch < 5; ++gch) {
        int col = c0 + gch * 8;
        bf16x8 v = *(const bf16x8*)(ep + row * EPITCH + col);
        size_t idx;
        if (TILED)
          idx = ((size_t)(col >> 6) * N_NODES + (bm + row)) * 64 + (col & 63);
        else
          idx = (size_t)(bm + row) * DP + col;
        *(bf16x8*)(C + idx) = v;
      }
    }
  } else {
    // ---- fused readout: relu(acc+bias1).Wro -> softmax -> graph bins ----
    float bv[5];
#pragma unroll
    for (int n = 0; n < 5; ++n) bv[n] = bias1[wc * 80 + n * 16 + cl];
#pragma unroll
    for (int m = 0; m < 2; ++m) {
#pragma unroll
      for (int r = 0; r < 4; ++r) {
        float s0 = 0.f, s1 = 0.f;
#pragma unroll
        for (int n = 0; n < 5; ++n) {
          int col = wc * 80 + n * 16 + cl;
          float v = fmaxf(acc[m][n][r] + bv[n], 0.f);
          s0 += v * wroL[2 * col];
          s1 += v * wroL[2 * col + 1];
        }
#pragma unroll
        for (int off = 1; off < 16; off <<= 1) {
          s0 += __shfl_xor(s0, off);
          s1 += __shfl_xor(s1, off);
        }
        if (cl == 0) {
          int row = wr * 32 + m * 16 + q * 4 + r;
          atomicAdd(&rowacc[2 * row], s0);
          atomicAdd(&rowacc[2 * row + 1], s1);
        }
      }
    }
    __syncthreads();
    if (t < 64) {
      float d0 = rowacc[2 * t] + bro[0];
      float d1 = rowacc[2 * t + 1] + bro[1];
      float mx = fmaxf(d0, d1);
      float e0 = expf(d0 - mx), e1 = expf(d1 - mx);
      float inv = 1.f / (e0 + e1);
      int g = gid[bm + t];
      atomicAdd(&binsL[2 * g], e0 * inv);
      atomicAdd(&binsL[2 * g + 1], e1 * inv);
    }
    __syncthreads();
    if (t < 2 * N_GRAPHS) {
      float v = binsL[t];
      if (v != 0.f) atomicAdd(&out[t], v);
    }
  }
}

// ===== padded adjacency build: one pass, no scan =====
// pad[d*CAP + pos] = src for pos = atomicAdd(cnt[d],1).  cnt zeroed by
// prep_kernel (runs before this).  Block 0 also zeroes d_out.
__global__ void scatter_pad(const int* __restrict__ src, const int* __restrict__ dst,
                            int* __restrict__ cnt, int* __restrict__ pad,
                            float* __restrict__ out, int out_n) {
  if (blockIdx.x == 0 && threadIdx.x < out_n) out[threadIdx.x] = 0.f;
  int e = blockIdx.x * blockDim.x + threadIdx.x;
  if (e >= N_EDGES) return;
  int d = dst[e];
  int pos = atomicAdd(&cnt[d], 1);
  if (pos < CAP) pad[(size_t)d * CAP + pos] = src[e];
}

// ========== SpMM aggregate: tiled gather, L2-resident per column phase ======
// 16-deep first batch (mean degree = 16 -> most rows covered by one volley).
__global__ __launch_bounds__(256) void spmm_tiled(
    const unsigned short* __restrict__ Mt, const int* __restrict__ cnt,
    const int* __restrict__ pad, unsigned short* __restrict__ agg) {
  const int tile = blockIdx.y;
  const int wv = threadIdx.x >> 6;
  const int l = threadIdx.x & 63;
  const int g = l >> 3;    // node group
  const int cs = l & 7;    // 16B slot within 128B slice
  const int node = blockIdx.x * 32 + wv * 8 + g;
  const unsigned short* base = Mt + (size_t)tile * N_NODES * 64 + cs * 8;
  const int* lst = pad + (size_t)node * CAP;

  const int j1 = min(cnt[node], CAP);
  int j = 0;
  float acc[8] = {};
  for (; j + 16 <= j1; j += 16) {
    bf16x8 v[16];
#pragma unroll
    for (int u = 0; u < 16; ++u)
      v[u] = *(const bf16x8*)(base + (size_t)lst[j + u] * 64);
#pragma unroll
    for (int u = 0; u < 16; ++u)
#pragma unroll
      for (int i = 0; i < 8; ++i) acc[i] += bf2f(v[u][i]);
  }
  if (j + 8 <= j1) {
    bf16x8 v[8];
#pragma unroll
    for (int u = 0; u < 8; ++u)
      v[u] = *(const bf16x8*)(base + (size_t)lst[j + u] * 64);
#pragma unroll
    for (int u = 0; u < 8; ++u)
#pragma unroll
      for (int i = 0; i < 8; ++i) acc[i] += bf2f(v[u][i]);
    j += 8;
  }
  if (j + 4 <= j1) {
    bf16x8 v[4];
#pragma unroll
    for (int u = 0; u < 4; ++u)
      v[u] = *(const bf16x8*)(base + (size_t)lst[j + u] * 64);
#pragma unroll
    for (int u = 0; u < 4; ++u)
#pragma unroll
      for (int i = 0; i < 8; ++i) acc[i] += bf2f(v[u][i]);
    j += 4;
  }
  for (; j < j1; ++j) {
    bf16x8 v = *(const bf16x8*)(base + (size_t)lst[j] * 64);
#pragma unroll
    for (int i = 0; i < 8; ++i) acc[i] += bf2f(v[i]);
  }
  bf16x8 o;
#pragma unroll
  for (int i = 0; i < 8; ++i) o[i] = f2bf(acc[i]);
  *(bf16x8*)(agg + (size_t)node * DP + tile * 64 + cs * 8) = o;
}

// ===== prep: 7 weight transposes + 7 bias copies + cnt zero =====
// Wt slots 0..6 = Wlift_t, Wf1t, Wo1t, Wf2t, Wo2t, Wf3t, Wo3t (all [n][k]).
// biasP slots 0..6 = bl, bf1, bo1, bf2, bo2, bf3, bo3 (zero-padded to DP).
// Blocks 0..63 also zero the cnt histogram (prep runs BEFORE scatter_pad).
struct WPtrs {
  const float* W[7];
  const float* b[7];
};

__global__ __launch_bounds__(256) void prep_kernel(
    WPtrs p, unsigned short* __restrict__ Wt, float* __restrict__ biasP,
    int* __restrict__ cnt) {
  __shared__ unsigned short ld[64][33];
  const int t = threadIdx.x;
  const int wb = blockIdx.x;  // 0..349

  if (wb < 64) cnt[wb * 256 + t] = 0;  // zero adjacency counters (fused)

  const int wi = wb / 50;                // 0..6
  const int blk = wb - wi * 50;
  const int kt = blk / 5;                // 10 k-tiles of 32
  const int nt = blk - kt * 5;           // 5 n-tiles of 64
  const int k0 = kt * 32, n0 = nt * 64;
  const float* W = p.W[wi];

#pragma unroll
  for (int ps = 0; ps < 8; ++ps) {
    int idx = t + 256 * ps;
    int rr = idx >> 6, cc = idx & 63;     // rr: k in tile, cc: n in tile
    float v = (k0 + rr < GD && n0 + cc < GD) ? W[(size_t)(k0 + rr) * GD + n0 + cc] : 0.f;
    ld[cc][rr] = f2bf(v);
  }
  __syncthreads();
#pragma unroll
  for (int ps = 0; ps < 8; ++ps) {
    int idx = t + 256 * ps;
    int nn = idx >> 5, kk = idx & 31;
    Wt[(size_t)wi * WSZ + (size_t)(n0 + nn) * DP + k0 + kk] = ld[nn][kk];
  }
  if (blk == 0) {  // fused bias copy for this weight's bias
    for (int i = t; i < DP; i += 256)
      biasP[(size_t)wi * DP + i] = (i < GD) ? p.b[wi][i] : 0.f;
  }
}

// ================= host =================
extern "C" void kernel_launch(void* const* d_in, const int* in_sizes, int n_in,
                              void* d_out, int out_size, void* d_ws, size_t ws_size,
                              hipStream_t stream) {
  const float* node_feats = (const float*)d_in[0];
  const float* W_ro = (const float*)d_in[15];
  const float* b_ro = (const float*)d_in[16];
  const int* src = (const int*)d_in[17];
  const int* dst = (const int*)d_in[18];
  const int* gid = (const int*)d_in[19];
  float* out = (float*)d_out;

  WPtrs wp;
  wp.W[0] = (const float*)d_in[1];   wp.b[0] = (const float*)d_in[2];   // Wlift/bl
  wp.W[1] = (const float*)d_in[3];   wp.b[1] = (const float*)d_in[4];   // Wf1/bf1
  wp.W[2] = (const float*)d_in[5];   wp.b[2] = (const float*)d_in[6];   // Wo1/bo1
  wp.W[3] = (const float*)d_in[7];   wp.b[3] = (const float*)d_in[8];   // Wf2/bf2
  wp.W[4] = (const float*)d_in[9];   wp.b[4] = (const float*)d_in[10];  // Wo2/bo2
  wp.W[5] = (const float*)d_in[11];  wp.b[5] = (const float*)d_in[12];  // Wf3/bf3
  wp.W[6] = (const float*)d_in[13];  wp.b[6] = (const float*)d_in[14];  // Wo3/bo3

  char* p = (char*)d_ws;
  unsigned short* X = (unsigned short*)p;  p += (size_t)N_NODES * DP * 2;
  unsigned short* Y = (unsigned short*)p;  p += (size_t)N_NODES * DP * 2;
  unsigned short* Wt = (unsigned short*)p; p += (size_t)7 * WSZ * 2;
  float* biasP = (float*)p;                p += 7 * DP * 4;
  int* cnt = (int*)p;                      p += N_NODES * 4;
  int* pad = (int*)p;                      p += (size_t)N_NODES * CAP * 4;

  // --- prep (weights + biases + cnt zero) THEN adjacency build ---
  prep_kernel<<<350, 256, 0, stream>>>(wp, Wt, biasP, cnt);
  scatter_pad<<<N_EDGES / 256, 256, 0, stream>>>(src, dst, cnt, pad, out, out_size);

  dim3 sgrid(N_NODES / 32, NTILE);  // (512, 5)

  // G1 (lift fused): h0 = feats@Wl+bl (no relu); msg1 = relu(h0@Wf1+bf1) [tiled]
  gemm_f<false, true, true, false, true><<<256, 512, 0, stream>>>(
      nullptr, node_feats, Wt + 0 * WSZ, biasP + 0 * DP,
      Wt + 1 * WSZ, biasP + 1 * DP, Y, nullptr, nullptr, nullptr, nullptr);
  spmm_tiled<<<sgrid, 256, 0, stream>>>(Y, cnt, pad, X);
  // F2: h1 = relu(agg1@Wo1+bo1) in LDS; msg2 = relu(h1@Wf2+bf2) [tiled]
  gemm_f<true, true, true, false, false><<<256, 512, 0, stream>>>(
      X, nullptr, Wt + 2 * WSZ, biasP + 2 * DP,
      Wt + 3 * WSZ, biasP + 3 * DP, Y, nullptr, nullptr, nullptr, nullptr);
  spmm_tiled<<<sgrid, 256, 0, stream>>>(Y, cnt, pad, X);
  // F3: h2 -> msg3 [tiled]
  gemm_f<true, true, true, false, false><<<256, 512, 0, stream>>>(
      X, nullptr, Wt + 4 * WSZ, biasP + 4 * DP,
      Wt + 5 * WSZ, biasP + 5 * DP, Y, nullptr, nullptr, nullptr, nullptr);
  spmm_tiled<<<sgrid, 256, 0, stream>>>(Y, cnt, pad, X);
  // G4: h3 = relu(agg3@Wo3+bo3) + fused readout
  gemm_f<true, false, false, true, false><<<256, 512, 0, stream>>>(
      X, nullptr, Wt + 6 * WSZ, biasP + 6 * DP, nullptr, nullptr, nullptr,
      W_ro, b_ro, gid, out);
}